// Round 1
// baseline (652.286 us; speedup 1.0000x reference)
//
#include <hip/hip_runtime.h>
#include <cstddef>

#define NB 32
#define NF 64
#define NL 8192
#define NP 96
#define NH 8
#define SPLIT 16

// ws layout in floats:
#define WS_MEAN 0          // 2048
#define WS_STD  2048       // 2048
#define WS_RSTD 4096       // 2048
#define WS_KV   6144       // NB*NH*64 = 16384
#define WS_Z    22528      // NB*NH*8  = 2048
#define WS_OUT2 24576      // NB*NP*NF = 196608
#define WS_YT   221184     // NB*NF*NL = 16777216  (total ~68 MB)

// ---------------- K1: RevIN stats per (b,f) ----------------
__global__ __launch_bounds__(256) void k_stats(const float* __restrict__ x,
                                               float* __restrict__ wmean,
                                               float* __restrict__ wstd,
                                               float* __restrict__ wrstd) {
  int bf = blockIdx.x;
  int tid = threadIdx.x;
  const float4* row4 = (const float4*)(x + (size_t)bf * NL);
  float s1 = 0.f, s2 = 0.f;
#pragma unroll
  for (int i = 0; i < NL / 4 / 256; i++) {
    float4 v = row4[tid + i * 256];
    s1 += v.x + v.y + v.z + v.w;
    s2 += v.x * v.x + v.y * v.y + v.z * v.z + v.w * v.w;
  }
  __shared__ float r1[256], r2[256];
  r1[tid] = s1; r2[tid] = s2;
  __syncthreads();
  for (int off = 128; off > 0; off >>= 1) {
    if (tid < off) { r1[tid] += r1[tid + off]; r2[tid] += r2[tid + off]; }
    __syncthreads();
  }
  if (tid == 0) {
    float m = r1[0] * (1.f / NL);
    float var = (r2[0] - (float)NL * m * m) * (1.f / (NL - 1));
    float sd = sqrtf(fmaxf(var, 0.f)) + 1e-5f;   // eps added to std (torch RevIN)
    wmean[bf] = m;
    wstd[bf] = sd;
    wrstd[bf] = 1.f / sd;
  }
}

// ---------------- K2: K/V projections + KV,Z accumulation ----------------
__global__ __launch_bounds__(256) void k_kv(
    const float* __restrict__ x,
    const float* __restrict__ gamma, const float* __restrict__ beta,
    const float* __restrict__ lnw, const float* __restrict__ lnb,
    const float* __restrict__ Wk, const float* __restrict__ bk,
    const float* __restrict__ Wv, const float* __restrict__ bv,
    const float* __restrict__ wmean, const float* __restrict__ wrstd,
    float* __restrict__ wKV, float* __restrict__ wZ) {
  int tid = threadIdx.x;
  int b = blockIdx.x >> 5;                 // 32 tiles of 256 l per b
  int l = ((blockIdx.x & 31) << 8) + tid;

  // RevIN + LayerNorm, h in registers (all W/bias/stat reads are wave-uniform -> s_load)
  float h[NF];
  float mu = 0.f;
#pragma unroll
  for (int f = 0; f < NF; f++) {
    float v = x[((size_t)(b * NF + f)) * NL + l];
    v = (v - wmean[b * NF + f]) * wrstd[b * NF + f] * gamma[f] + beta[f];
    h[f] = v;
    mu += v;
  }
  mu *= (1.f / NF);
  float var = 0.f;
#pragma unroll
  for (int f = 0; f < NF; f++) { float d = h[f] - mu; var += d * d; }
  float rs = rsqrtf(var * (1.f / NF) + 1e-5f);
#pragma unroll
  for (int f = 0; f < NF; f++) h[f] = (h[f] - mu) * rs * lnw[f] + lnb[f];

  __shared__ float kbuf[256 * 8], vbuf[256 * 8];
  __shared__ float red[256];
  __shared__ float zred[32];

  int chunk = tid >> 6;          // 0..3
  int dd = (tid & 63) >> 3;      // 0..7
  int ee = tid & 7;              // 0..7

  for (int hh = 0; hh < NH; hh++) {
    float k8[8], v8[8];
#pragma unroll
    for (int j = 0; j < 8; j++) { k8[j] = bk[hh * 8 + j]; v8[j] = bv[hh * 8 + j]; }
#pragma unroll
    for (int f = 0; f < NF; f++) {
      float hf = h[f];
#pragma unroll
      for (int j = 0; j < 8; j++) {
        k8[j] = fmaf(hf, Wk[(hh * 8 + j) * NF + f], k8[j]);
        v8[j] = fmaf(hf, Wv[(hh * 8 + j) * NF + f], v8[j]);
      }
    }
#pragma unroll
    for (int j = 0; j < 8; j++) {
      float kk = k8[j];
      kbuf[tid * 8 + j] = (kk > 0.f) ? (kk + 1.f) : __expf(kk);  // phi = elu+1
      vbuf[tid * 8 + j] = v8[j];
    }
    __syncthreads();
    // KV[d][e] partial over this block's 256 l values, 4 chunks x 64 (d,e) pairs
    float s = 0.f;
    int t0 = chunk * 64;
#pragma unroll 8
    for (int t = 0; t < 64; t++)
      s = fmaf(kbuf[(t0 + t) * 8 + dd], vbuf[(t0 + t) * 8 + ee], s);
    red[tid] = s;
    if (tid < 32) {
      int c2 = tid >> 3, d2 = tid & 7;
      float zs = 0.f;
#pragma unroll 8
      for (int t = 0; t < 64; t++) zs += kbuf[(c2 * 64 + t) * 8 + d2];
      zred[tid] = zs;
    }
    __syncthreads();
    if (tid < 64)
      atomicAdd(&wKV[(b * NH + hh) * 64 + tid],
                red[tid] + red[tid + 64] + red[tid + 128] + red[tid + 192]);
    if (tid < 8)
      atomicAdd(&wZ[(b * NH + hh) * 8 + tid],
                zred[tid] + zred[tid + 8] + zred[tid + 16] + zred[tid + 24]);
    __syncthreads();
  }
}

// ---------------- K3: Q proj + linear attention + Wo + residual -> yT ----------------
__global__ __launch_bounds__(256) void k_attn(
    const float* __restrict__ x,
    const float* __restrict__ gamma, const float* __restrict__ beta,
    const float* __restrict__ lnw, const float* __restrict__ lnb,
    const float* __restrict__ Wq, const float* __restrict__ bq,
    const float* __restrict__ Wo, const float* __restrict__ bo,
    const float* __restrict__ wmean, const float* __restrict__ wrstd,
    const float* __restrict__ wKV, const float* __restrict__ wZ,
    float* __restrict__ yT) {
  int tid = threadIdx.x;
  int b = blockIdx.x >> 5;
  int l = ((blockIdx.x & 31) << 8) + tid;

  float h[NF], yacc[NF];
  {
    float xn[NF];
    float mu = 0.f;
#pragma unroll
    for (int f = 0; f < NF; f++) {
      float v = x[((size_t)(b * NF + f)) * NL + l];
      v = (v - wmean[b * NF + f]) * wrstd[b * NF + f] * gamma[f] + beta[f];
      xn[f] = v; mu += v;
    }
    mu *= (1.f / NF);
    float var = 0.f;
#pragma unroll
    for (int f = 0; f < NF; f++) { float d = xn[f] - mu; var += d * d; }
    float rs = rsqrtf(var * (1.f / NF) + 1e-5f);
#pragma unroll
    for (int f = 0; f < NF; f++) {
      h[f] = (xn[f] - mu) * rs * lnw[f] + lnb[f];
      yacc[f] = xn[f] + bo[f];   // residual + output bias folded in
    }
  }

  for (int hh = 0; hh < NH; hh++) {
    float q8[8];
#pragma unroll
    for (int j = 0; j < 8; j++) {
      float q = bq[hh * 8 + j];
#pragma unroll
      for (int f = 0; f < NF; f++)
        q = fmaf(h[f], Wq[(hh * 8 + j) * NF + f], q);
      q8[j] = (q > 0.f) ? (q + 1.f) : __expf(q);   // phi
    }
    float norm = 1e-6f;
#pragma unroll
    for (int d = 0; d < 8; d++) norm = fmaf(q8[d], wZ[(b * NH + hh) * 8 + d], norm);
    float inv = 1.f / norm;
    float out8[8];
#pragma unroll
    for (int e = 0; e < 8; e++) {
      float s = 0.f;
#pragma unroll
      for (int d = 0; d < 8; d++)
        s = fmaf(q8[d], wKV[(b * NH + hh) * 64 + d * 8 + e], s);
      out8[e] = s * inv;
    }
#pragma unroll
    for (int f = 0; f < NF; f++) {
      float a = yacc[f];
#pragma unroll
      for (int e = 0; e < 8; e++)
        a = fmaf(out8[e], Wo[f * NF + hh * 8 + e], a);
      yacc[f] = a;
    }
  }
#pragma unroll
  for (int f = 0; f < NF; f++)
    yT[((size_t)(b * NF + f)) * NL + l] = yacc[f];   // (B,F,L) layout, coalesced in l
}

// ---------------- K4: temporal GEMM out2[b,p,f] = sum_l Wlin[p,l]*yT[b,f,l] ----------------
__global__ __launch_bounds__(256) void k_temporal(
    const float* __restrict__ yT, const float* __restrict__ Wlin,
    float* __restrict__ out2) {
  __shared__ float yt[NF * 65];   // +1 pad to break bank conflicts
  __shared__ float wt[NP * 65];
  int tid = threadIdx.x;
  int b = blockIdx.x / SPLIT;
  int kc = blockIdx.x % SPLIT;
  int f0 = (tid & 15) * 4;
  int p0 = (tid >> 4) * 6;
  float acc[4][6];
#pragma unroll
  for (int i = 0; i < 4; i++)
#pragma unroll
    for (int j = 0; j < 6; j++) acc[i][j] = 0.f;

  for (int ks = 0; ks < (NL / SPLIT) / 64; ks++) {
    int l0 = kc * (NL / SPLIT) + ks * 64;
#pragma unroll
    for (int i = 0; i < 4; i++) {            // 64x64 y tile
      int flat4 = tid + i * 256;
      int row = flat4 >> 4, c4 = flat4 & 15;
      float4 v = *(const float4*)(yT + ((size_t)(b * NF + row)) * NL + l0 + c4 * 4);
      float* dst = &yt[row * 65 + c4 * 4];
      dst[0] = v.x; dst[1] = v.y; dst[2] = v.z; dst[3] = v.w;
    }
#pragma unroll
    for (int i = 0; i < 6; i++) {            // 96x64 W tile
      int flat4 = tid + i * 256;
      int row = flat4 >> 4, c4 = flat4 & 15;
      float4 v = *(const float4*)(Wlin + (size_t)row * NL + l0 + c4 * 4);
      float* dst = &wt[row * 65 + c4 * 4];
      dst[0] = v.x; dst[1] = v.y; dst[2] = v.z; dst[3] = v.w;
    }
    __syncthreads();
#pragma unroll 4
    for (int k = 0; k < 64; k++) {
      float yv[4], wv[6];
#pragma unroll
      for (int i = 0; i < 4; i++) yv[i] = yt[(f0 + i) * 65 + k];
#pragma unroll
      for (int j = 0; j < 6; j++) wv[j] = wt[(p0 + j) * 65 + k];
#pragma unroll
      for (int i = 0; i < 4; i++)
#pragma unroll
        for (int j = 0; j < 6; j++)
          acc[i][j] = fmaf(yv[i], wv[j], acc[i][j]);
    }
    __syncthreads();
  }
#pragma unroll
  for (int i = 0; i < 4; i++)
#pragma unroll
    for (int j = 0; j < 6; j++)
      atomicAdd(&out2[((size_t)(b * NP + p0 + j)) * NF + f0 + i], acc[i][j]);
}

// ---------------- K5: +blin, RevIN denorm, projector ----------------
__global__ __launch_bounds__(64) void k_final(
    const float* __restrict__ out2, const float* __restrict__ blin,
    const float* __restrict__ gamma, const float* __restrict__ beta,
    const float* __restrict__ wmean, const float* __restrict__ wstd,
    const float* __restrict__ Wp, const float* __restrict__ bp,
    float* __restrict__ out) {
  int b = blockIdx.x / NP;
  int p = blockIdx.x % NP;
  int f = threadIdx.x;
  float v = out2[((size_t)(b * NP + p)) * NF + f] + blin[p];
  v = (v - beta[f]) / gamma[f];
  v = v * wstd[b * NF + f] + wmean[b * NF + f];
  float s = v * Wp[f];
#pragma unroll
  for (int off = 32; off > 0; off >>= 1)
    s += __shfl_down(s, off, 64);
  if (f == 0) out[blockIdx.x] = s + bp[0];
}

extern "C" void kernel_launch(void* const* d_in, const int* in_sizes, int n_in,
                              void* d_out, int out_size, void* d_ws, size_t ws_size,
                              hipStream_t stream) {
  const float* x     = (const float*)d_in[0];
  const float* gamma = (const float*)d_in[1];
  const float* beta  = (const float*)d_in[2];
  const float* lnw   = (const float*)d_in[3];
  const float* lnb   = (const float*)d_in[4];
  const float* Wq    = (const float*)d_in[5];
  const float* bq    = (const float*)d_in[6];
  const float* Wk    = (const float*)d_in[7];
  const float* bk    = (const float*)d_in[8];
  const float* Wv    = (const float*)d_in[9];
  const float* bv    = (const float*)d_in[10];
  const float* Wo    = (const float*)d_in[11];
  const float* bo    = (const float*)d_in[12];
  const float* Wlin  = (const float*)d_in[13];
  const float* blin  = (const float*)d_in[14];
  const float* Wp    = (const float*)d_in[15];
  const float* bp    = (const float*)d_in[16];
  float* out = (float*)d_out;
  float* ws  = (float*)d_ws;

  float* wmean = ws + WS_MEAN;
  float* wstd  = ws + WS_STD;
  float* wrstd = ws + WS_RSTD;
  float* wKV   = ws + WS_KV;
  float* wZ    = ws + WS_Z;
  float* wout2 = ws + WS_OUT2;
  float* wyT   = ws + WS_YT;

  // zero the atomic accumulators: KV, Z, out2 are contiguous [WS_KV, WS_OUT2+B*P*F)
  hipMemsetAsync(wKV, 0, (size_t)(16384 + 2048 + 196608) * sizeof(float), stream);

  k_stats<<<NB * NF, 256, 0, stream>>>(x, wmean, wstd, wrstd);
  k_kv<<<NB * 32, 256, 0, stream>>>(x, gamma, beta, lnw, lnb, Wk, bk, Wv, bv,
                                    wmean, wrstd, wKV, wZ);
  k_attn<<<NB * 32, 256, 0, stream>>>(x, gamma, beta, lnw, lnb, Wq, bq, Wo, bo,
                                      wmean, wrstd, wKV, wZ, wyT);
  k_temporal<<<NB * SPLIT, 256, 0, stream>>>(wyT, Wlin, wout2);
  k_final<<<NB * NP, 64, 0, stream>>>(wout2, blin, gamma, beta, wmean, wstd, Wp, bp, out);
}